// Round 1
// 927.306 us; speedup vs baseline: 1.0137x; 1.0137x over previous
//
#include <hip/hip_runtime.h>

typedef __attribute__((ext_vector_type(8))) short short8;
typedef __attribute__((ext_vector_type(4))) float floatx4;

#define MFMA(a,b,c) __builtin_amdgcn_mfma_f32_16x16x32_bf16(a,b,c,0,0,0)

__device__ __forceinline__ ushort f2bf(float f){ union{float f;uint i;}x; x.f=f; return (ushort)((x.i + 0x7fffu + ((x.i>>16)&1u))>>16); }
__device__ __forceinline__ short8 lds8(const ushort* p){ return *(const short8*)p; }

// ---------------------------------------------------------------------------
// Prologue: convert GEMM weights fp32 -> bf16 into ws.
// qkv_w @0 (27648), proj_w @27648 (9216), fc1_w @36864 (36864), fc2_w @73728 (36864)
// ---------------------------------------------------------------------------
__global__ void convw_kernel(const float* __restrict__ qkvw,
                             const float* __restrict__ projw,
                             const float* __restrict__ f1w,
                             const float* __restrict__ f2w,
                             ushort* __restrict__ wb)
{
  int i = blockIdx.x*256 + threadIdx.x;
  float v;
  if      (i < 27648)  v = qkvw[i];
  else if (i < 36864)  v = projw[i-27648];
  else if (i < 73728)  v = f1w[i-36864];
  else if (i < 110592) v = f2w[i-73728];
  else return;
  wb[i] = f2bf(v);
}

// ---------------------------------------------------------------------------
// Fully fused Swin block. One workgroup (256 thr = 4 waves) per window.
// LDS cut to ~39KB (vs 63KB) for 4 blocks/CU:
//  - attention processed per-head (Q/K/V buffers for ONE head at a time)
//  - residual written to global out in phase 3; phase 5 does out[pos] += mlp,
//    so the MLP hidden buffer overlays the fp32 residual region.
// ---------------------------------------------------------------------------
__global__ __launch_bounds__(256,4) void swin_block_kernel(
    const float* __restrict__ x,
    const float* __restrict__ g1, const float* __restrict__ b1v,
    const ushort* __restrict__ qkv_wb, const float* __restrict__ qkv_b,
    const ushort* __restrict__ proj_wb, const float* __restrict__ proj_b,
    const float* __restrict__ g2, const float* __restrict__ b2v,
    const ushort* __restrict__ fc1_wb, const float* __restrict__ fc1_b,
    const ushort* __restrict__ fc2_wb, const float* __restrict__ fc2_b,
    float* __restrict__ out)
{
  __shared__ __align__(16) ushort sm[19200];        // 38400 B
  __shared__ int sid[64];
  ushort* xn  = sm;                    // 64x104 bf16: LN1 out -> attn O -> LN2 out
  ushort* Qh  = sm + 6656;             // [64][32]  current head
  ushort* Kh  = sm + 8704;             // [64][40]  current head
  ushort* Vh  = sm + 11264;            // [32][72]  [d][token], current head
  ushort* Pb  = sm + 13568;            // [64][72]
  float*  xrb = (float*)(sm + 6656);   // 64x96 fp32 residual (phases 3-4 only)
  ushort* hb  = sm + 6656;             // 32x392 bf16 MLP hidden (phase 5, overlays xrb)

  const int tid  = threadIdx.x;
  const int w    = blockIdx.x;
  const int b    = w >> 10;
  const int wh   = (w >> 5) & 31;
  const int wwn  = w & 31;
  const int lane = tid & 63;
  const int wv   = tid >> 6;
  const int quad = lane >> 4;
  const int ln   = lane & 15;

  // ---- Phase 0: LN1 + shifted-window gather (4 threads per token) ----
  {
    const int n = tid >> 2, q = tid & 3;
    if (n < 49) {
      const int i = n / 7, j = n - 7*i;
      int hh = wh*7 + i + 3; if (hh >= 224) hh -= 224;
      int w2 = wwn*7 + j + 3; if (w2 >= 224) w2 -= 224;
      if (q == 0) {
        const int rr = (wh < 31) ? 0 : ((i < 4) ? 1 : 2);
        const int cr = (wwn < 31) ? 0 : ((j < 4) ? 1 : 2);
        sid[n] = rr*3 + cr;
      }
      const float* px = x + (((size_t)b*224 + hh)*224 + w2)*96 + q*24;
      float v[24]; float s = 0.f, s2 = 0.f;
      const float4* p4 = (const float4*)px;
      #pragma unroll
      for (int t = 0; t < 6; ++t) { float4 u = p4[t];
        v[t*4+0]=u.x; v[t*4+1]=u.y; v[t*4+2]=u.z; v[t*4+3]=u.w; }
      #pragma unroll
      for (int c = 0; c < 24; ++c) { s += v[c]; s2 += v[c]*v[c]; }
      s  += __shfl_xor(s, 1);  s  += __shfl_xor(s, 2);
      s2 += __shfl_xor(s2, 1); s2 += __shfl_xor(s2, 2);
      const float mu = s * (1.f/96.f);
      const float rs = rsqrtf(s2*(1.f/96.f) - mu*mu + 1e-5f);
      ushort* row = xn + n*104 + q*24;
      #pragma unroll
      for (int c = 0; c < 24; ++c)
        row[c] = f2bf((v[c]-mu)*rs*g1[q*24+c] + b1v[q*24+c]);
    }
    for (int idx = tid; idx < 15*104; idx += 256) xn[49*104 + idx] = 0;  // pad rows
  }
  __syncthreads();

  // A fragments for the qkv GEMM, register-cached across the whole head loop
  // (xn is then dead as an input and can be reused as attention output ob).
  short8 a0, a1, a2;
  {
    const ushort* arow = xn + (wv*16 + ln)*104 + quad*8;
    a0 = lds8(arow); a1 = lds8(arow+32); a2 = lds8(arow+64);
  }
  int idrv[4], idcv[4];
  #pragma unroll
  for (int reg = 0; reg < 4; ++reg) {
    const int r = wv*16 + quad*4 + reg;
    idrv[reg] = (r < 49) ? sid[r] : -1;
  }
  #pragma unroll
  for (int nt = 0; nt < 4; ++nt) {
    const int c = nt*16 + ln;
    idcv[nt] = (c < 49) ? sid[c] : -2;
  }

  // ---- Phases 1+2: per-head qkv GEMM + attention ----
  ushort* ob = xn;
  for (int h = 0; h < 3; ++h) {
    // qkv GEMM, head h only: 6 col-tiles (2 Q, 2 K, 2 V)
    #pragma unroll
    for (int nt = 0; nt < 6; ++nt) {
      const int sec = nt >> 1, sub = nt & 1;           // sec: 0=Q 1=K 2=V
      const int colw = sec*96 + h*32 + sub*16 + ln;    // column in [0,288)
      const ushort* wrow = qkv_wb + colw*96 + quad*8;
      floatx4 acc = {0.f,0.f,0.f,0.f};
      acc = MFMA(a0, lds8(wrow),    acc);
      acc = MFMA(a1, lds8(wrow+32), acc);
      acc = MFMA(a2, lds8(wrow+64), acc);
      const float bias = qkv_b[colw];
      const int d = sub*16 + ln;                       // 0..31
      #pragma unroll
      for (int reg = 0; reg < 4; ++reg) {
        const int r = wv*16 + quad*4 + reg;            // token row
        float val = acc[reg] + bias;
        if (sec == 0)      Qh[r*32 + d] = f2bf(val * 0.17677669529663689f);
        else if (sec == 1) Kh[r*40 + d] = f2bf(val);
        else               Vh[d*72 + r] = f2bf(val);
      }
    }
    __syncthreads();

    // QK^T + masked softmax -> Pb
    {
      short8 aq = lds8(Qh + (wv*16 + ln)*32 + quad*8);
      floatx4 sc[4];
      #pragma unroll
      for (int nt = 0; nt < 4; ++nt) {
        short8 kb = lds8(Kh + (nt*16 + ln)*40 + quad*8);
        floatx4 z = {0.f,0.f,0.f,0.f};
        sc[nt] = MFMA(aq, kb, z);               // S[r][c]
      }
      #pragma unroll
      for (int reg = 0; reg < 4; ++reg) {
        float t[4]; float mx = -1e30f;
        #pragma unroll
        for (int nt = 0; nt < 4; ++nt) {
          float tv = -1e30f;
          if (idrv[reg] >= 0 && idcv[nt] >= 0)
            tv = sc[nt][reg] + ((idrv[reg] == idcv[nt]) ? 0.f : -100.f);
          t[nt] = tv; mx = fmaxf(mx, tv);
        }
        mx = fmaxf(mx, __shfl_xor(mx, 1));
        mx = fmaxf(mx, __shfl_xor(mx, 2));
        mx = fmaxf(mx, __shfl_xor(mx, 4));
        mx = fmaxf(mx, __shfl_xor(mx, 8));
        float e[4], sum = 0.f;
        #pragma unroll
        for (int nt = 0; nt < 4; ++nt) {
          e[nt] = (t[nt] > -1e29f) ? __expf(t[nt] - mx) : 0.f;
          sum += e[nt];
        }
        sum += __shfl_xor(sum, 1);
        sum += __shfl_xor(sum, 2);
        sum += __shfl_xor(sum, 4);
        sum += __shfl_xor(sum, 8);
        const float inv = (sum > 0.f) ? 1.f/sum : 0.f;
        #pragma unroll
        for (int nt = 0; nt < 4; ++nt)
          Pb[(wv*16 + quad*4 + reg)*72 + nt*16 + ln] = f2bf(e[nt]*inv);
      }
    }
    __syncthreads();

    // P @ V -> ob columns [h*32, h*32+32)
    {
      short8 p0 = lds8(Pb + (wv*16 + ln)*72 + quad*8);
      short8 p1 = lds8(Pb + (wv*16 + ln)*72 + 32 + quad*8);
      #pragma unroll
      for (int ntd = 0; ntd < 2; ++ntd) {
        floatx4 accO = {0.f,0.f,0.f,0.f};
        accO = MFMA(p0, lds8(Vh + (ntd*16+ln)*72 + quad*8),      accO);
        accO = MFMA(p1, lds8(Vh + (ntd*16+ln)*72 + 32 + quad*8), accO);
        #pragma unroll
        for (int reg = 0; reg < 4; ++reg)
          ob[(wv*16 + quad*4 + reg)*104 + h*32 + ntd*16 + ln] = f2bf(accO[reg]);
      }
    }
    __syncthreads();
  }

  // ---- Phase 3: proj + residual -> xrb (fp32 LDS, for LN2) AND global out ----
  {
    const ushort* arow = ob + (wv*16 + ln)*104 + quad*8;
    short8 o0 = lds8(arow), o1 = lds8(arow+32), o2 = lds8(arow+64);
    for (int nt = 0; nt < 6; ++nt) {
      const ushort* wrow = proj_wb + (nt*16 + ln)*96 + quad*8;
      floatx4 acc = {0.f,0.f,0.f,0.f};
      acc = MFMA(o0, lds8(wrow),    acc);
      acc = MFMA(o1, lds8(wrow+32), acc);
      acc = MFMA(o2, lds8(wrow+64), acc);
      const int col = nt*16 + ln;
      const float bias = proj_b[col];
      #pragma unroll
      for (int reg = 0; reg < 4; ++reg) {
        const int r = wv*16 + quad*4 + reg;
        if (r < 49) {
          const int i = r / 7, j = r - 7*i;
          int hh = wh*7 + i + 3; if (hh >= 224) hh -= 224;
          int w2 = wwn*7 + j + 3; if (w2 >= 224) w2 -= 224;
          const size_t pos = (((size_t)b*224 + hh)*224 + w2)*96 + col;
          const float val = x[pos] + acc[reg] + bias;
          xrb[r*96 + col] = val;
          out[pos] = val;                        // residual persisted to global
        }
      }
    }
    for (int idx = tid; idx < 15*96; idx += 256) xrb[49*96 + idx] = 0.f;  // pads
  }
  __syncthreads();

  // ---- Phase 4: LN2 from xrb -> xn (bf16) ----
  {
    const int n = tid >> 2, q = tid & 3;
    const float4* p4 = (const float4*)(xrb + n*96 + q*24);
    float v[24]; float s = 0.f, s2 = 0.f;
    #pragma unroll
    for (int t = 0; t < 6; ++t) { float4 u = p4[t];
      v[t*4+0]=u.x; v[t*4+1]=u.y; v[t*4+2]=u.z; v[t*4+3]=u.w; }
    #pragma unroll
    for (int c = 0; c < 24; ++c) { s += v[c]; s2 += v[c]*v[c]; }
    s  += __shfl_xor(s, 1);  s  += __shfl_xor(s, 2);
    s2 += __shfl_xor(s2, 1); s2 += __shfl_xor(s2, 2);
    const float mu = s * (1.f/96.f);
    const float rs = rsqrtf(s2*(1.f/96.f) - mu*mu + 1e-5f);
    ushort* row = xn + n*104 + q*24;
    #pragma unroll
    for (int c = 0; c < 24; ++c)
      row[c] = f2bf((v[c]-mu)*rs*g2[q*24+c] + b2v[q*24+c]);
  }
  __syncthreads();   // xrb dead after this point; hb overlays it

  // ---- Phase 5: MLP in two 32-token halves (hb = 32x392) ----
  const int rloc = (wv & 1) * 16;
  const int p    = wv >> 1;
  for (int half = 0; half < 2; ++half) {
    {
      const ushort* arow = xn + (half*32 + rloc + ln)*104 + quad*8;
      short8 m0 = lds8(arow), m1 = lds8(arow+32), m2 = lds8(arow+64);
      for (int t = 0; t < 12; ++t) {
        const int nt = p*12 + t;
        const ushort* wrow = fc1_wb + (nt*16 + ln)*96 + quad*8;
        floatx4 acc = {0.f,0.f,0.f,0.f};
        acc = MFMA(m0, lds8(wrow),    acc);
        acc = MFMA(m1, lds8(wrow+32), acc);
        acc = MFMA(m2, lds8(wrow+64), acc);
        const int col = nt*16 + ln;
        const float bias = fc1_b[col];
        #pragma unroll
        for (int reg = 0; reg < 4; ++reg) {
          const float vv = acc[reg] + bias;
          hb[(rloc + quad*4 + reg)*392 + col] =
              f2bf(0.5f*vv*(1.f + erff(vv*0.70710678118654752f)));
        }
      }
    }
    __syncthreads();
    {
      short8 ap[12];
      const ushort* prow = hb + (rloc + ln)*392 + quad*8;
      #pragma unroll
      for (int kt = 0; kt < 12; ++kt) ap[kt] = lds8(prow + kt*32);
      for (int t = 0; t < 3; ++t) {
        const int nt = p*3 + t;
        const ushort* wrow = fc2_wb + (nt*16 + ln)*384 + quad*8;
        floatx4 acc = {0.f,0.f,0.f,0.f};
        #pragma unroll
        for (int kt = 0; kt < 12; ++kt) acc = MFMA(ap[kt], lds8(wrow + kt*32), acc);
        const int col = nt*16 + ln;
        const float bias = fc2_b[col];
        #pragma unroll
        for (int reg = 0; reg < 4; ++reg) {
          const int r = half*32 + rloc + quad*4 + reg;
          if (r < 49) {
            const int i = r / 7, j = r - 7*i;
            int hh = wh*7 + i + 3; if (hh >= 224) hh -= 224;
            int w2 = wwn*7 + j + 3; if (w2 >= 224) w2 -= 224;
            const size_t pos = (((size_t)b*224 + hh)*224 + w2)*96 + col;
            out[pos] += acc[reg] + bias;        // RMW: residual was stored in phase 3
          }
        }
      }
    }
    __syncthreads();
  }
}

extern "C" void kernel_launch(void* const* d_in, const int* in_sizes, int n_in,
                              void* d_out, int out_size, void* d_ws, size_t ws_size,
                              hipStream_t stream) {
  // Size-based remap (identity in practice — kept as insurance).
  int ix=-1, iq=-1, ip=-1, if1=-1, if2=-1, largest=0;
  for (int i = 0; i < n_in; ++i) {
    const int s = in_sizes[i];
    if (s == 38535168 && ix < 0) ix = i;
    else if (s == 27648 && iq < 0) iq = i;
    else if (s == 9216 && ip < 0) ip = i;
    else if (s == 36864) { if (if1 < 0) if1 = i; else if (if2 < 0) if2 = i; }
    if (in_sizes[i] >= in_sizes[largest]) largest = i;
  }
  if (ix < 0) ix = largest;
  if (iq < 0) iq = 4;
  if (ip < 0) ip = 6;
  if (if1 < 0) if1 = 10;
  if (if2 < 0) if2 = 12;

  const float* x    = (const float*)d_in[ix];
  const float* n1g  = (const float*)d_in[2];
  const float* n1b  = (const float*)d_in[3];
  const float* qkvw = (const float*)d_in[iq];
  const float* qkvb = (const float*)d_in[5];
  const float* pw   = (const float*)d_in[ip];
  const float* pb   = (const float*)d_in[7];
  const float* n2g  = (const float*)d_in[8];
  const float* n2b  = (const float*)d_in[9];
  const float* f1w  = (const float*)d_in[if1];
  const float* f1b  = (const float*)d_in[11];
  const float* f2w  = (const float*)d_in[if2];
  const float* f2b  = (const float*)d_in[13];
  float* outp = (float*)d_out;
  ushort* wb = (ushort*)d_ws;

  convw_kernel<<<432, 256, 0, stream>>>(qkvw, pw, f1w, f2w, wb);
  swin_block_kernel<<<8192, 256, 0, stream>>>(
      x, n1g, n1b, wb, qkvb, wb + 27648, pb,
      n2g, n2b, wb + 36864, f1b, wb + 73728, f2b, outp);
}